// Round 1
// baseline (2612.178 us; speedup 1.0000x reference)
//
#include <hip/hip_runtime.h>
#include <hip/hip_bf16.h>

#define BB 4
#define NS 16384
#define NG 2048
#define DD 128

// ---------------------------------------------------------------------------
// Pre-encoder: H[r][e] = relu(sum_d X[r][d]*W[d][e] + bias[e]); X:[R][128]
// 64 rows/block, 256 threads: thread = (row = tid>>2, eo = tid&3 -> 32 e's)
// ---------------------------------------------------------------------------
__global__ __launch_bounds__(256) void pre_gemm_k(
    const float* __restrict__ X, const float* __restrict__ W,
    const float* __restrict__ bias, float* __restrict__ H) {
  __shared__ float lx[64][132];  // pad 132 -> stride 528B, 2-way banks (free)
  const int tid = threadIdx.x;
  const long row0 = (long)blockIdx.x * 64;
#pragma unroll
  for (int i = 0; i < 8; ++i) {
    const int f = i * 1024 + tid * 4;
    const float4 v = *(const float4*)(X + row0 * DD + f);
    *(float4*)&lx[f >> 7][f & 127] = v;
  }
  __syncthreads();
  const int row = tid >> 2, eo = tid & 3;
  float acc[32];
#pragma unroll
  for (int j = 0; j < 32; ++j) acc[j] = 0.f;
  const float* Wb = W + eo * 32;
  for (int d = 0; d < DD; d += 4) {
    const float4 xv = *(const float4*)&lx[row][d];
    const float xa[4] = {xv.x, xv.y, xv.z, xv.w};
#pragma unroll
    for (int k = 0; k < 4; ++k) {
      const float x = xa[k];
      const float* wr = Wb + (d + k) * DD;
#pragma unroll
      for (int q = 0; q < 8; ++q) {
        const float4 w4 = *(const float4*)(wr + q * 4);
        acc[q * 4 + 0] += x * w4.x;
        acc[q * 4 + 1] += x * w4.y;
        acc[q * 4 + 2] += x * w4.z;
        acc[q * 4 + 3] += x * w4.w;
      }
    }
  }
  float* hp = H + (row0 + row) * DD + eo * 32;
  const float* bp = bias + eo * 32;
#pragma unroll
  for (int q = 0; q < 8; ++q) {
    float4 o;
    o.x = fmaxf(acc[q * 4 + 0] + bp[q * 4 + 0], 0.f);
    o.y = fmaxf(acc[q * 4 + 1] + bp[q * 4 + 1], 0.f);
    o.z = fmaxf(acc[q * 4 + 2] + bp[q * 4 + 2], 0.f);
    o.w = fmaxf(acc[q * 4 + 3] + bp[q * 4 + 3], 0.f);
    *(float4*)(hp + q * 4) = o;
  }
}

// ---------------------------------------------------------------------------
// msg_s: xs_out[n][e] = (sum_m w[n][m]*xg_h[m][e]) / (sum_m w[n][m] + 1e-8)
// Also writes rsinv[n] = 1/(rowsum+1e-8) for msg_g.
// 16 surface rows/block, 256 threads. Phase A: (ar=tid&15, grp=tid>>4) each
// computes 1 w per 16-m chunk into LDS (double-buffered). Phase B:
// (row=tid>>4, eo=tid&15 -> 8 e's) accumulates with wave-uniform zero-skip.
// ---------------------------------------------------------------------------
__global__ __launch_bounds__(256) void msg_s_k(
    const float* __restrict__ vs, const float* __restrict__ vg,
    const float* __restrict__ xg_h, float* __restrict__ xs_o,
    float* __restrict__ rsinv) {
  __shared__ float wlds[2][16][20];
  __shared__ float wsred[16][17];
  __shared__ float invws[16];
  const int tid = threadIdx.x;
  const int b = blockIdx.y;
  const int row0 = blockIdx.x * 16;
  const int ar = tid & 15, grp = tid >> 4;
  const long vsi = ((long)b * NS + row0 + ar) * 3;
  const float asx = vs[vsi + 0], asy = vs[vsi + 1], asz = vs[vsi + 2];
  const float* __restrict__ vgb = vg + (long)b * NG * 3;
  float ws_part = 0.f;
  const int row = tid >> 4, eo = tid & 15;
  float acc[8];
#pragma unroll
  for (int j = 0; j < 8; ++j) acc[j] = 0.f;
  const float* __restrict__ xgb = xg_h + (long)b * NG * DD + eo * 8;

  auto phaseA = [&](int c, int buf) {
    const int m = c * 16 + grp;
    const float dx = asx - vgb[m * 3 + 0];
    const float dy = asy - vgb[m * 3 + 1];
    const float dz = asz - vgb[m * 3 + 2];
    const float d2 = dx * dx + dy * dy + dz * dz;
    const float w = (d2 < 64.f) ? __expf(d2 * (-1.f / 6.25f)) : 0.f;
    wlds[buf][ar][grp] = w;
    ws_part += w;
  };

  phaseA(0, 0);
  const int NC = NG / 16;
  for (int c = 0; c < NC; ++c) {
    __syncthreads();
    if (c + 1 < NC) phaseA(c + 1, (c + 1) & 1);
    const int buf = c & 1;
    const int m0 = c * 16;
#pragma unroll
    for (int m4 = 0; m4 < 4; ++m4) {
      const float4 w4 = *(const float4*)&wlds[buf][row][m4 * 4];
      const float wa[4] = {w4.x, w4.y, w4.z, w4.w};
#pragma unroll
      for (int k = 0; k < 4; ++k) {
        const float wv = wa[k];
        if (__any(wv != 0.f)) {
          const float* g = xgb + (long)(m0 + m4 * 4 + k) * DD;
          const float4 g0 = *(const float4*)g;
          const float4 g1 = *(const float4*)(g + 4);
          acc[0] += wv * g0.x; acc[1] += wv * g0.y;
          acc[2] += wv * g0.z; acc[3] += wv * g0.w;
          acc[4] += wv * g1.x; acc[5] += wv * g1.y;
          acc[6] += wv * g1.z; acc[7] += wv * g1.w;
        }
      }
    }
  }
  wsred[grp][ar] = ws_part;
  __syncthreads();
  if (tid < 16) {
    float s = 1e-8f;
#pragma unroll
    for (int g2 = 0; g2 < 16; ++g2) s += wsred[g2][tid];
    const float inv = 1.f / s;
    invws[tid] = inv;
    rsinv[(long)b * NS + row0 + tid] = inv;
  }
  __syncthreads();
  const float inv = invws[row];
  float* op = xs_o + ((long)b * NS + row0 + row) * DD + eo * 8;
  float4 s0, s1;
  s0.x = acc[0] * inv; s0.y = acc[1] * inv;
  s0.z = acc[2] * inv; s0.w = acc[3] * inv;
  s1.x = acc[4] * inv; s1.y = acc[5] * inv;
  s1.z = acc[6] * inv; s1.w = acc[7] * inv;
  *(float4*)op = s0;
  *(float4*)(op + 4) = s1;
}

// ---------------------------------------------------------------------------
// msg_g: xg_out[m][e] = sum_n (w[n][m] * rsinv[n]) * xs_h[n][e]
// 16 graph rows/block; streams all Ns surface nodes in 16-n chunks.
// ---------------------------------------------------------------------------
__global__ __launch_bounds__(256) void msg_g_k(
    const float* __restrict__ vs, const float* __restrict__ vg,
    const float* __restrict__ xs_h, const float* __restrict__ rsinv,
    float* __restrict__ xg_o) {
  __shared__ float wlds[2][16][20];
  const int tid = threadIdx.x;
  const int b = blockIdx.y;
  const int g0 = blockIdx.x * 16;
  const int ar = tid & 15, grp = tid >> 4;
  const long vgi = ((long)b * NG + g0 + ar) * 3;
  const float agx = vg[vgi + 0], agy = vg[vgi + 1], agz = vg[vgi + 2];
  const float* __restrict__ vsb = vs + (long)b * NS * 3;
  const float* __restrict__ rsb = rsinv + (long)b * NS;
  const int row = tid >> 4, eo = tid & 15;
  float acc[8];
#pragma unroll
  for (int j = 0; j < 8; ++j) acc[j] = 0.f;
  const float* __restrict__ xsb = xs_h + (long)b * NS * DD + eo * 8;

  auto phaseA = [&](int c, int buf) {
    const int n = c * 16 + grp;
    const float dx = agx - vsb[n * 3 + 0];
    const float dy = agy - vsb[n * 3 + 1];
    const float dz = agz - vsb[n * 3 + 2];
    const float d2 = dx * dx + dy * dy + dz * dz;
    float w = 0.f;
    if (d2 < 64.f) w = __expf(d2 * (-1.f / 6.25f)) * rsb[n];
    wlds[buf][ar][grp] = w;
  };

  phaseA(0, 0);
  const int NC = NS / 16;
  for (int c = 0; c < NC; ++c) {
    __syncthreads();
    if (c + 1 < NC) phaseA(c + 1, (c + 1) & 1);
    const int buf = c & 1;
    const int n0 = c * 16;
#pragma unroll
    for (int m4 = 0; m4 < 4; ++m4) {
      const float4 w4 = *(const float4*)&wlds[buf][row][m4 * 4];
      const float wa[4] = {w4.x, w4.y, w4.z, w4.w};
#pragma unroll
      for (int k = 0; k < 4; ++k) {
        const float wv = wa[k];
        if (__any(wv != 0.f)) {
          const float* g = xsb + (long)(n0 + m4 * 4 + k) * DD;
          const float4 g0 = *(const float4*)g;
          const float4 g1 = *(const float4*)(g + 4);
          acc[0] += wv * g0.x; acc[1] += wv * g0.y;
          acc[2] += wv * g0.z; acc[3] += wv * g0.w;
          acc[4] += wv * g1.x; acc[5] += wv * g1.y;
          acc[6] += wv * g1.z; acc[7] += wv * g1.w;
        }
      }
    }
  }
  float* op = xg_o + ((long)b * NG + g0 + row) * DD + eo * 8;
  float4 s0, s1;
  s0.x = acc[0]; s0.y = acc[1]; s0.z = acc[2]; s0.w = acc[3];
  s1.x = acc[4]; s1.y = acc[5]; s1.z = acc[6]; s1.w = acc[7];
  *(float4*)op = s0;
  *(float4*)(op + 4) = s1;
}

// ---------------------------------------------------------------------------
// Post block: out = relu([Ha, Hb] @ W + bias), K=256. 32 rows/block.
// thread = (row = tid>>3, eo = tid&7 -> 16 e's)
// ---------------------------------------------------------------------------
__global__ __launch_bounds__(256) void post_gemm_k(
    const float* __restrict__ Ha, const float* __restrict__ Hb,
    const float* __restrict__ W, const float* __restrict__ bias,
    float* __restrict__ out, const int bshift, const int nmask,
    const int noff) {
  __shared__ float lx[32][260];
  const int tid = threadIdx.x;
  const long rg0 = (long)blockIdx.x * 32;
#pragma unroll
  for (int i = 0; i < 8; ++i) {
    const int f = i * 1024 + tid * 4;
    const int r = f >> 8, c = f & 255;
    const long rowg = rg0 + r;
    float4 v;
    if (c < 128)
      v = *(const float4*)(Ha + rowg * DD + c);
    else
      v = *(const float4*)(Hb + rowg * DD + (c - 128));
    *(float4*)&lx[r][c] = v;
  }
  __syncthreads();
  const int row = tid >> 3, eo = tid & 7;
  float acc[16];
#pragma unroll
  for (int j = 0; j < 16; ++j) acc[j] = 0.f;
  const float* Wb = W + eo * 16;
  for (int d = 0; d < 256; d += 4) {
    const float4 xv = *(const float4*)&lx[row][d];
    const float xa[4] = {xv.x, xv.y, xv.z, xv.w};
#pragma unroll
    for (int k = 0; k < 4; ++k) {
      const float x = xa[k];
      const float* wr = Wb + (d + k) * DD;
#pragma unroll
      for (int q = 0; q < 4; ++q) {
        const float4 w4 = *(const float4*)(wr + q * 4);
        acc[q * 4 + 0] += x * w4.x;
        acc[q * 4 + 1] += x * w4.y;
        acc[q * 4 + 2] += x * w4.z;
        acc[q * 4 + 3] += x * w4.w;
      }
    }
  }
  const long rowg = rg0 + row;
  const long bb = rowg >> bshift;
  const long n = rowg & nmask;
  float* op = out + (bb * (NS + NG) + noff + n) * DD + eo * 16;
  const float* bp = bias + eo * 16;
#pragma unroll
  for (int q = 0; q < 4; ++q) {
    float4 o;
    o.x = fmaxf(acc[q * 4 + 0] + bp[q * 4 + 0], 0.f);
    o.y = fmaxf(acc[q * 4 + 1] + bp[q * 4 + 1], 0.f);
    o.z = fmaxf(acc[q * 4 + 2] + bp[q * 4 + 2], 0.f);
    o.w = fmaxf(acc[q * 4 + 3] + bp[q * 4 + 3], 0.f);
    *(float4*)(op + q * 4) = o;
  }
}

// ---------------------------------------------------------------------------
extern "C" void kernel_launch(void* const* d_in, const int* in_sizes, int n_in,
                              void* d_out, int out_size, void* d_ws,
                              size_t ws_size, hipStream_t stream) {
  const float* xs = (const float*)d_in[0];
  const float* xg = (const float*)d_in[1];
  const float* vs = (const float*)d_in[2];
  const float* vg = (const float*)d_in[3];
  const float* Ws_pre = (const float*)d_in[4];
  const float* bs_pre = (const float*)d_in[5];
  const float* Wg_pre = (const float*)d_in[6];
  const float* bg_pre = (const float*)d_in[7];
  const float* Ws_post = (const float*)d_in[8];
  const float* bs_post = (const float*)d_in[9];
  const float* Wg_post = (const float*)d_in[10];
  const float* bg_post = (const float*)d_in[11];
  float* out = (float*)d_out;

  float* w = (float*)d_ws;
  float* xs_h = w;                                 // B*NS*D f32
  float* xg_h = xs_h + (size_t)BB * NS * DD;       // B*NG*D
  float* xs_o = xg_h + (size_t)BB * NG * DD;       // B*NS*D
  float* xg_o = xs_o + (size_t)BB * NS * DD;       // B*NG*D
  float* rsv = xg_o + (size_t)BB * NG * DD;        // B*NS

  pre_gemm_k<<<BB * NS / 64, 256, 0, stream>>>(xs, Ws_pre, bs_pre, xs_h);
  pre_gemm_k<<<BB * NG / 64, 256, 0, stream>>>(xg, Wg_pre, bg_pre, xg_h);
  msg_s_k<<<dim3(NS / 16, BB), 256, 0, stream>>>(vs, vg, xg_h, xs_o, rsv);
  msg_g_k<<<dim3(NG / 16, BB), 256, 0, stream>>>(vs, vg, xs_h, rsv, xg_o);
  post_gemm_k<<<BB * NS / 32, 256, 0, stream>>>(xs_h, xs_o, Ws_post, bs_post,
                                                out, 14, NS - 1, 0);
  post_gemm_k<<<BB * NG / 32, 256, 0, stream>>>(xg_h, xg_o, Wg_post, bg_post,
                                                out, 11, NG - 1, NS);
}

// Round 2
// 361.429 us; speedup vs baseline: 7.2274x; 7.2274x over previous
//
#include <hip/hip_runtime.h>
#include <hip/hip_bf16.h>

#define BB 4
#define NS 16384
#define NG 2048
#define DD 128
#define SPLITG 4

typedef short bf16x8 __attribute__((ext_vector_type(8)));
typedef unsigned short u16x8 __attribute__((ext_vector_type(8)));
typedef unsigned short u16x4 __attribute__((ext_vector_type(4)));
typedef float f32x4 __attribute__((ext_vector_type(4)));

__device__ __forceinline__ unsigned short f2bf(float x) {
  unsigned int u = __builtin_bit_cast(unsigned int, x);
  u += 0x7FFFu + ((u >> 16) & 1u);
  return (unsigned short)(u >> 16);
}
__device__ __forceinline__ float bf2f(unsigned short h) {
  unsigned int u = ((unsigned int)h) << 16;
  return __builtin_bit_cast(float, u);
}

// ---------------------------------------------------------------------------
// posprep: per node build two 16-bf16 vectors so that dot(pos1_a, pos2_b) = d2.
// pos1 = [-2hx,-2hy,-2hz, -2lx,-2ly,-2lz, -2hx,-2hy,-2hz, -2lx,-2ly,-2lz, nh, nl, 1, 1]
// pos2 = [ hx, hy, hz,  hx, hy, hz,  lx, ly, lz,  lx, ly, lz, 1, 1, nh, nl]
// slots 0-11: -2*v_a.v_b (hi/lo split); 12-13: |v_a|^2; 14-15: |v_b|^2.
// ---------------------------------------------------------------------------
__global__ __launch_bounds__(256) void posprep_k(
    const float* __restrict__ v, int nNodes, unsigned short* __restrict__ pos1,
    unsigned short* __restrict__ pos2) {
  int i = blockIdx.x * 256 + threadIdx.x;
  if (i >= nNodes) return;
  float x = v[i * 3 + 0], y = v[i * 3 + 1], z = v[i * 3 + 2];
  unsigned short hx = f2bf(x), hy = f2bf(y), hz = f2bf(z);
  float fx = bf2f(hx), fy = bf2f(hy), fz = bf2f(hz);
  unsigned short lx = f2bf(x - fx), ly = f2bf(y - fy), lz = f2bf(z - fz);
  float n = x * x + y * y + z * z;
  unsigned short nh = f2bf(n);
  unsigned short nl = f2bf(n - bf2f(nh));
  unsigned short m2hx = f2bf(-2.f * fx), m2hy = f2bf(-2.f * fy),
                 m2hz = f2bf(-2.f * fz);
  unsigned short m2lx = f2bf(-2.f * bf2f(lx)), m2ly = f2bf(-2.f * bf2f(ly)),
                 m2lz = f2bf(-2.f * bf2f(lz));
  const unsigned short one = 0x3F80;
  u16x8 a0 = {m2hx, m2hy, m2hz, m2lx, m2ly, m2lz, m2hx, m2hy};
  u16x8 a1 = {m2hz, m2lx, m2ly, m2lz, nh, nl, one, one};
  u16x8 b0 = {hx, hy, hz, hx, hy, hz, lx, ly};
  u16x8 b1 = {lz, lx, ly, lz, one, one, nh, nl};
  *(u16x8*)(pos1 + (long)i * 16) = a0;
  *(u16x8*)(pos1 + (long)i * 16 + 8) = a1;
  *(u16x8*)(pos2 + (long)i * 16) = b0;
  *(u16x8*)(pos2 + (long)i * 16 + 8) = b1;
}

// W [K][128] f32 -> Wt [128][K] bf16
__global__ __launch_bounds__(256) void wprep_k(const float* __restrict__ W,
                                               int kshift,
                                               unsigned short* __restrict__ Wt) {
  int idx = blockIdx.x * 256 + threadIdx.x;
  int K = 1 << kshift;
  int e = idx >> kshift, k = idx & (K - 1);
  Wt[(long)e * K + k] = f2bf(W[(long)k * 128 + e]);
}

// ---------------------------------------------------------------------------
// pre GEMM: H = relu(X @ W + b), K=128, bf16 MFMA. 64 rows/block, 4 waves.
// ---------------------------------------------------------------------------
__global__ __launch_bounds__(256) void pre_mfma_k(
    const float* __restrict__ X, const unsigned short* __restrict__ Wt,
    const float* __restrict__ bias, unsigned short* __restrict__ Hrm) {
  int tid = threadIdx.x, l = tid & 63, w = tid >> 6;
  int g = l >> 4, r = l & 15;
  long row0 = (long)blockIdx.x * 64 + w * 16;
  const float* xrow = X + (row0 + r) * DD;
  f32x4 z4 = {0.f, 0.f, 0.f, 0.f};
  f32x4 acc[8];
#pragma unroll
  for (int i = 0; i < 8; ++i) acc[i] = z4;
#pragma unroll
  for (int ks = 0; ks < 4; ++ks) {
    float4 v0 = *(const float4*)(xrow + ks * 32 + 8 * g);
    float4 v1 = *(const float4*)(xrow + ks * 32 + 8 * g + 4);
    bf16x8 a;
    a[0] = (short)f2bf(v0.x); a[1] = (short)f2bf(v0.y);
    a[2] = (short)f2bf(v0.z); a[3] = (short)f2bf(v0.w);
    a[4] = (short)f2bf(v1.x); a[5] = (short)f2bf(v1.y);
    a[6] = (short)f2bf(v1.z); a[7] = (short)f2bf(v1.w);
#pragma unroll
    for (int ct = 0; ct < 8; ++ct) {
      bf16x8 b = *reinterpret_cast<const bf16x8*>(Wt + (ct * 16 + r) * DD +
                                                  ks * 32 + 8 * g);
      acc[ct] = __builtin_amdgcn_mfma_f32_16x16x32_bf16(a, b, acc[ct], 0, 0, 0);
    }
  }
#pragma unroll
  for (int ct = 0; ct < 8; ++ct) {
    float bv = bias[ct * 16 + r];
#pragma unroll
    for (int r4 = 0; r4 < 4; ++r4) {
      long row = row0 + 4 * g + r4;
      Hrm[row * DD + ct * 16 + r] = f2bf(fmaxf(acc[ct][r4] + bv, 0.f));
    }
  }
}

// bf16 [R][128] -> [128][R]
__global__ __launch_bounds__(256) void transpose_k(
    const unsigned short* __restrict__ H, unsigned short* __restrict__ HT,
    int R) {
  __shared__ unsigned short lds[64 * 136];
  int tid = threadIdx.x;
  long r0 = (long)blockIdx.x * 64;
#pragma unroll
  for (int q = 0; q < 4; ++q) {
    int idx = q * 2048 + tid * 8;
    int rr = idx >> 7, cc = idx & 127;
    *(u16x8*)&lds[rr * 136 + cc] =
        *reinterpret_cast<const u16x8*>(H + (r0 + rr) * 128 + cc);
  }
  __syncthreads();
  int e = tid >> 1, half = tid & 1;
#pragma unroll
  for (int q = 0; q < 4; ++q) {
    u16x8 v;
#pragma unroll
    for (int i = 0; i < 8; ++i)
      v[i] = lds[(half * 32 + q * 8 + i) * 136 + e];
    *reinterpret_cast<u16x8*>(HT + (long)e * R + r0 + half * 32 + q * 8) = v;
  }
}

// ---------------------------------------------------------------------------
// msg_s: per block 64 surface rows (4 waves x 16), stream Ng in 64-col chunks.
// cross-MFMA gives d2 tile -> w (exp) -> wlds (padded) -> msg MFMA vs xg_hT.
// Also computes rowsums -> rsinv, normalizes, writes xs_o bf16 row-major.
// ---------------------------------------------------------------------------
__global__ __launch_bounds__(256) void msg_s_k(
    const unsigned short* __restrict__ pos1_s,
    const unsigned short* __restrict__ pos2_g,
    const unsigned short* __restrict__ xg_hT, unsigned short* __restrict__ xs_o,
    float* __restrict__ rsinv) {
  __shared__ unsigned short ldsB[128 * 72];
  __shared__ unsigned short wlds[4][16 * 72];
  int tid = threadIdx.x, l = tid & 63, w = tid >> 6;
  int g = l >> 4, r = l & 15;
  int b = blockIdx.y;
  long row0 = (long)blockIdx.x * 64 + w * 16;
  const long BNG = (long)BB * NG;
  f32x4 z4 = {0.f, 0.f, 0.f, 0.f};
  bf16x8 zero8 = {0, 0, 0, 0, 0, 0, 0, 0};
  bf16x8 aP = zero8;
  if (g < 2)
    aP = *reinterpret_cast<const bf16x8*>(pos1_s +
                                          ((long)b * NS + row0 + r) * 16 + 8 * g);
  f32x4 acc[8];
#pragma unroll
  for (int i = 0; i < 8; ++i) acc[i] = z4;
  float rs[4] = {0.f, 0.f, 0.f, 0.f};
  u16x8 st[4];
#pragma unroll
  for (int q = 0; q < 4; ++q) {
    int idx = q * 256 + tid;
    int e = idx >> 3, k16 = idx & 7;
    st[q] = *reinterpret_cast<const u16x8*>(xg_hT + (long)e * BNG +
                                            (long)b * NG + 0 + k16 * 8);
  }
  for (int c = 0; c < NG / 64; ++c) {
#pragma unroll
    for (int q = 0; q < 4; ++q) {
      int idx = q * 256 + tid;
      int e = idx >> 3, k16 = idx & 7;
      *(u16x8*)&ldsB[e * 72 + k16 * 8] = st[q];
    }
    __syncthreads();
    if (c + 1 < NG / 64) {
      int m0n = (c + 1) * 64;
#pragma unroll
      for (int q = 0; q < 4; ++q) {
        int idx = q * 256 + tid;
        int e = idx >> 3, k16 = idx & 7;
        st[q] = *reinterpret_cast<const u16x8*>(xg_hT + (long)e * BNG +
                                                (long)b * NG + m0n + k16 * 8);
      }
    }
    int m0 = c * 64;
#pragma unroll
    for (int ct = 0; ct < 4; ++ct) {
      bf16x8 bP = zero8;
      if (g < 2)
        bP = *reinterpret_cast<const bf16x8*>(
            pos2_g + ((long)b * NG + m0 + ct * 16 + r) * 16 + 8 * g);
      f32x4 S = __builtin_amdgcn_mfma_f32_16x16x32_bf16(aP, bP, z4, 0, 0, 0);
#pragma unroll
      for (int r4 = 0; r4 < 4; ++r4) {
        float d2 = S[r4];
        float wv = (d2 < 64.f) ? __expf(d2 * -0.16f) : 0.f;
        rs[r4] += wv;
        wlds[w][(4 * g + r4) * 72 + ct * 16 + r] = f2bf(wv);
      }
    }
    __syncthreads();
    bf16x8 af0 = *reinterpret_cast<const bf16x8*>(&wlds[w][r * 72 + 8 * g]);
    bf16x8 af1 = *reinterpret_cast<const bf16x8*>(&wlds[w][r * 72 + 8 * g + 32]);
#pragma unroll
    for (int ct2 = 0; ct2 < 8; ++ct2) {
      bf16x8 bm0 =
          *reinterpret_cast<const bf16x8*>(&ldsB[(ct2 * 16 + r) * 72 + 8 * g]);
      acc[ct2] =
          __builtin_amdgcn_mfma_f32_16x16x32_bf16(af0, bm0, acc[ct2], 0, 0, 0);
      bf16x8 bm1 = *reinterpret_cast<const bf16x8*>(
          &ldsB[(ct2 * 16 + r) * 72 + 8 * g + 32]);
      acc[ct2] =
          __builtin_amdgcn_mfma_f32_16x16x32_bf16(af1, bm1, acc[ct2], 0, 0, 0);
    }
    __syncthreads();
  }
#pragma unroll
  for (int r4 = 0; r4 < 4; ++r4) {
    rs[r4] += __shfl_xor(rs[r4], 1, 64);
    rs[r4] += __shfl_xor(rs[r4], 2, 64);
    rs[r4] += __shfl_xor(rs[r4], 4, 64);
    rs[r4] += __shfl_xor(rs[r4], 8, 64);
  }
  float rsi[4];
#pragma unroll
  for (int r4 = 0; r4 < 4; ++r4) rsi[r4] = 1.f / (rs[r4] + 1e-8f);
  if (r == 0) {
#pragma unroll
    for (int r4 = 0; r4 < 4; ++r4)
      rsinv[(long)b * NS + row0 + 4 * g + r4] = rsi[r4];
  }
#pragma unroll
  for (int ct2 = 0; ct2 < 8; ++ct2) {
#pragma unroll
    for (int r4 = 0; r4 < 4; ++r4) {
      long rowg = (long)b * NS + row0 + 4 * g + r4;
      xs_o[rowg * DD + ct2 * 16 + r] = f2bf(acc[ct2][r4] * rsi[r4]);
    }
  }
}

// ---------------------------------------------------------------------------
// msg_g: per block 64 graph rows, stream a split of Ns; w' = w * rsinv[n].
// Writes f32 partials (summed by reduce_k).
// ---------------------------------------------------------------------------
__global__ __launch_bounds__(256) void msg_g_k(
    const unsigned short* __restrict__ pos1_g,
    const unsigned short* __restrict__ pos2_s,
    const unsigned short* __restrict__ xs_hT, const float* __restrict__ rsinv,
    float* __restrict__ part) {
  __shared__ unsigned short ldsB[128 * 72];
  __shared__ unsigned short wlds[4][16 * 72];
  int tid = threadIdx.x, l = tid & 63, w = tid >> 6;
  int g = l >> 4, r = l & 15;
  int b = blockIdx.y, sp = blockIdx.z;
  long row0 = (long)blockIdx.x * 64 + w * 16;
  long nbeg = (long)sp * (NS / SPLITG);
  const long BNS = (long)BB * NS;
  f32x4 z4 = {0.f, 0.f, 0.f, 0.f};
  bf16x8 zero8 = {0, 0, 0, 0, 0, 0, 0, 0};
  bf16x8 aP = zero8;
  if (g < 2)
    aP = *reinterpret_cast<const bf16x8*>(pos1_g +
                                          ((long)b * NG + row0 + r) * 16 + 8 * g);
  f32x4 acc[8];
#pragma unroll
  for (int i = 0; i < 8; ++i) acc[i] = z4;
  u16x8 st[4];
#pragma unroll
  for (int q = 0; q < 4; ++q) {
    int idx = q * 256 + tid;
    int e = idx >> 3, k16 = idx & 7;
    st[q] = *reinterpret_cast<const u16x8*>(xs_hT + (long)e * BNS +
                                            (long)b * NS + nbeg + k16 * 8);
  }
  const int NC = (NS / SPLITG) / 64;
  for (int c = 0; c < NC; ++c) {
#pragma unroll
    for (int q = 0; q < 4; ++q) {
      int idx = q * 256 + tid;
      int e = idx >> 3, k16 = idx & 7;
      *(u16x8*)&ldsB[e * 72 + k16 * 8] = st[q];
    }
    __syncthreads();
    if (c + 1 < NC) {
      long n0n = nbeg + (long)(c + 1) * 64;
#pragma unroll
      for (int q = 0; q < 4; ++q) {
        int idx = q * 256 + tid;
        int e = idx >> 3, k16 = idx & 7;
        st[q] = *reinterpret_cast<const u16x8*>(xs_hT + (long)e * BNS +
                                                (long)b * NS + n0n + k16 * 8);
      }
    }
    long m0 = nbeg + (long)c * 64;
#pragma unroll
    for (int ct = 0; ct < 4; ++ct) {
      bf16x8 bP = zero8;
      if (g < 2)
        bP = *reinterpret_cast<const bf16x8*>(
            pos2_s + ((long)b * NS + m0 + ct * 16 + r) * 16 + 8 * g);
      float rv = rsinv[(long)b * NS + m0 + ct * 16 + r];
      f32x4 S = __builtin_amdgcn_mfma_f32_16x16x32_bf16(aP, bP, z4, 0, 0, 0);
#pragma unroll
      for (int r4 = 0; r4 < 4; ++r4) {
        float d2 = S[r4];
        float wv = (d2 < 64.f) ? __expf(d2 * -0.16f) * rv : 0.f;
        wlds[w][(4 * g + r4) * 72 + ct * 16 + r] = f2bf(wv);
      }
    }
    __syncthreads();
    bf16x8 af0 = *reinterpret_cast<const bf16x8*>(&wlds[w][r * 72 + 8 * g]);
    bf16x8 af1 = *reinterpret_cast<const bf16x8*>(&wlds[w][r * 72 + 8 * g + 32]);
#pragma unroll
    for (int ct2 = 0; ct2 < 8; ++ct2) {
      bf16x8 bm0 =
          *reinterpret_cast<const bf16x8*>(&ldsB[(ct2 * 16 + r) * 72 + 8 * g]);
      acc[ct2] =
          __builtin_amdgcn_mfma_f32_16x16x32_bf16(af0, bm0, acc[ct2], 0, 0, 0);
      bf16x8 bm1 = *reinterpret_cast<const bf16x8*>(
          &ldsB[(ct2 * 16 + r) * 72 + 8 * g + 32]);
      acc[ct2] =
          __builtin_amdgcn_mfma_f32_16x16x32_bf16(af1, bm1, acc[ct2], 0, 0, 0);
    }
    __syncthreads();
  }
  long base = (long)sp * ((long)BB * NG * DD);
#pragma unroll
  for (int ct2 = 0; ct2 < 8; ++ct2) {
#pragma unroll
    for (int r4 = 0; r4 < 4; ++r4) {
      long rowg = (long)b * NG + row0 + 4 * g + r4;
      part[base + rowg * DD + ct2 * 16 + r] = acc[ct2][r4];
    }
  }
}

__global__ __launch_bounds__(256) void reduce_k(const float* __restrict__ part,
                                                unsigned short* __restrict__ xg_o) {
  long i = ((long)blockIdx.x * 256 + threadIdx.x) * 4;
  const long S = (long)BB * NG * DD;
  f32x4 s = *(const f32x4*)(part + i);
  s += *(const f32x4*)(part + S + i);
  s += *(const f32x4*)(part + 2 * S + i);
  s += *(const f32x4*)(part + 3 * S + i);
  u16x4 o;
#pragma unroll
  for (int k = 0; k < 4; ++k) o[k] = f2bf(s[k]);
  *reinterpret_cast<u16x4*>(xg_o + i) = o;
}

// ---------------------------------------------------------------------------
// post GEMM: out = relu([Ha|Hb] @ W + b), K=256, f32 output to d_out.
// ---------------------------------------------------------------------------
__global__ __launch_bounds__(256) void post_mfma_k(
    const unsigned short* __restrict__ Ha, const unsigned short* __restrict__ Hb,
    const unsigned short* __restrict__ Wt, const float* __restrict__ bias,
    float* __restrict__ out, int shift, int mask, int off) {
  int tid = threadIdx.x, l = tid & 63, w = tid >> 6;
  int g = l >> 4, r = l & 15;
  long row0 = (long)blockIdx.x * 64 + w * 16;
  const unsigned short* ha = Ha + (row0 + r) * DD;
  const unsigned short* hb = Hb + (row0 + r) * DD;
  f32x4 z4 = {0.f, 0.f, 0.f, 0.f};
  f32x4 acc[8];
#pragma unroll
  for (int i = 0; i < 8; ++i) acc[i] = z4;
#pragma unroll
  for (int ks = 0; ks < 8; ++ks) {
    const unsigned short* src = (ks < 4) ? (ha + ks * 32) : (hb + (ks - 4) * 32);
    bf16x8 a = *reinterpret_cast<const bf16x8*>(src + 8 * g);
#pragma unroll
    for (int ct = 0; ct < 8; ++ct) {
      bf16x8 b = *reinterpret_cast<const bf16x8*>(Wt + (ct * 16 + r) * 256 +
                                                  ks * 32 + 8 * g);
      acc[ct] = __builtin_amdgcn_mfma_f32_16x16x32_bf16(a, b, acc[ct], 0, 0, 0);
    }
  }
#pragma unroll
  for (int ct = 0; ct < 8; ++ct) {
    float bv = bias[ct * 16 + r];
#pragma unroll
    for (int r4 = 0; r4 < 4; ++r4) {
      long rowg = row0 + 4 * g + r4;
      long bb = rowg >> shift;
      long n = rowg & mask;
      out[(bb * (NS + NG) + off + n) * DD + ct * 16 + r] =
          fmaxf(acc[ct][r4] + bv, 0.f);
    }
  }
}

// ---------------------------------------------------------------------------
extern "C" void kernel_launch(void* const* d_in, const int* in_sizes, int n_in,
                              void* d_out, int out_size, void* d_ws,
                              size_t ws_size, hipStream_t stream) {
  const float* xs = (const float*)d_in[0];
  const float* xg = (const float*)d_in[1];
  const float* vs = (const float*)d_in[2];
  const float* vg = (const float*)d_in[3];
  const float* Ws_pre = (const float*)d_in[4];
  const float* bs_pre = (const float*)d_in[5];
  const float* Wg_pre = (const float*)d_in[6];
  const float* bg_pre = (const float*)d_in[7];
  const float* Ws_post = (const float*)d_in[8];
  const float* bs_post = (const float*)d_in[9];
  const float* Wg_post = (const float*)d_in[10];
  const float* bg_post = (const float*)d_in[11];
  float* out = (float*)d_out;

  char* p = (char*)d_ws;
  unsigned short* pos1_s = (unsigned short*)p; p += (size_t)BB * NS * 16 * 2;
  unsigned short* pos2_s = (unsigned short*)p; p += (size_t)BB * NS * 16 * 2;
  unsigned short* pos1_g = (unsigned short*)p; p += (size_t)BB * NG * 16 * 2;
  unsigned short* pos2_g = (unsigned short*)p; p += (size_t)BB * NG * 16 * 2;
  unsigned short* WtS_pre = (unsigned short*)p; p += (size_t)128 * 128 * 2;
  unsigned short* WtG_pre = (unsigned short*)p; p += (size_t)128 * 128 * 2;
  unsigned short* WtS_post = (unsigned short*)p; p += (size_t)128 * 256 * 2;
  unsigned short* WtG_post = (unsigned short*)p; p += (size_t)128 * 256 * 2;
  unsigned short* xs_h = (unsigned short*)p; p += (size_t)BB * NS * DD * 2;
  unsigned short* xg_h = (unsigned short*)p; p += (size_t)BB * NG * DD * 2;
  unsigned short* xs_hT = (unsigned short*)p; p += (size_t)BB * NS * DD * 2;
  unsigned short* xg_hT = (unsigned short*)p; p += (size_t)BB * NG * DD * 2;
  unsigned short* xs_o = (unsigned short*)p; p += (size_t)BB * NS * DD * 2;
  unsigned short* xg_o = (unsigned short*)p; p += (size_t)BB * NG * DD * 2;
  float* rsv = (float*)p; p += (size_t)BB * NS * 4;
  float* part = (float*)p; p += (size_t)SPLITG * BB * NG * DD * 4;

  posprep_k<<<(BB * NS) / 256, 256, 0, stream>>>(vs, BB * NS, pos1_s, pos2_s);
  posprep_k<<<(BB * NG) / 256, 256, 0, stream>>>(vg, BB * NG, pos1_g, pos2_g);
  wprep_k<<<64, 256, 0, stream>>>(Ws_pre, 7, WtS_pre);
  wprep_k<<<64, 256, 0, stream>>>(Wg_pre, 7, WtG_pre);
  wprep_k<<<128, 256, 0, stream>>>(Ws_post, 8, WtS_post);
  wprep_k<<<128, 256, 0, stream>>>(Wg_post, 8, WtG_post);
  pre_mfma_k<<<BB * NS / 64, 256, 0, stream>>>(xs, WtS_pre, bs_pre, xs_h);
  pre_mfma_k<<<BB * NG / 64, 256, 0, stream>>>(xg, WtG_pre, bg_pre, xg_h);
  transpose_k<<<BB * NS / 64, 256, 0, stream>>>(xs_h, xs_hT, BB * NS);
  transpose_k<<<BB * NG / 64, 256, 0, stream>>>(xg_h, xg_hT, BB * NG);
  msg_s_k<<<dim3(NS / 64, BB), 256, 0, stream>>>(pos1_s, pos2_g, xg_hT, xs_o,
                                                 rsv);
  msg_g_k<<<dim3(NG / 64, BB, SPLITG), 256, 0, stream>>>(pos1_g, pos2_s, xs_hT,
                                                         rsv, part);
  reduce_k<<<(BB * NG * DD) / 4 / 256, 256, 0, stream>>>(part, xg_o);
  post_mfma_k<<<BB * NS / 64, 256, 0, stream>>>(xs_h, xs_o, WtS_post, bs_post,
                                                out, 14, NS - 1, 0);
  post_mfma_k<<<BB * NG / 64, 256, 0, stream>>>(xg_h, xg_o, WtG_post, bg_post,
                                                out, 11, NG - 1, NS);
}

// Round 3
// 273.146 us; speedup vs baseline: 9.5633x; 1.3232x over previous
//
#include <hip/hip_runtime.h>
#include <hip/hip_bf16.h>

#define BB 4
#define NS 16384
#define NG 2048
#define DD 128
#define SPLITG 8
#define C2 (-0.23083120f)  // -log2(e)/sigma^2

typedef short bf16x8 __attribute__((ext_vector_type(8)));
typedef unsigned short u16x8 __attribute__((ext_vector_type(8)));
typedef float f32x4 __attribute__((ext_vector_type(4)));
typedef float f32x16 __attribute__((ext_vector_type(16)));
typedef int i32x4 __attribute__((ext_vector_type(4)));

__device__ __forceinline__ unsigned short f2bf(float x) {
  unsigned int u = __builtin_bit_cast(unsigned int, x);
  u += 0x7FFFu + ((u >> 16) & 1u);
  return (unsigned short)(u >> 16);
}
__device__ __forceinline__ float bf2f(unsigned short h) {
  unsigned int u = ((unsigned int)h) << 16;
  return __builtin_bit_cast(float, u);
}

// pack 8 f32 -> bf16x8 A-fragment via cvt_pk + permlane32_swap (T12 recipe)
#define PACK_SWAP(e0, e1, e2, e3, e4, e5, e6, e7, OUT)                       \
  {                                                                          \
    unsigned pq0, pq1, pq2, pq3;                                             \
    asm("v_cvt_pk_bf16_f32 %0, %1, %2" : "=v"(pq0) : "v"(e0), "v"(e1));      \
    asm("v_cvt_pk_bf16_f32 %0, %1, %2" : "=v"(pq1) : "v"(e2), "v"(e3));      \
    asm("v_cvt_pk_bf16_f32 %0, %1, %2" : "=v"(pq2) : "v"(e4), "v"(e5));      \
    asm("v_cvt_pk_bf16_f32 %0, %1, %2" : "=v"(pq3) : "v"(e6), "v"(e7));      \
    asm("v_permlane32_swap_b32 %0, %1" : "+v"(pq0), "+v"(pq2));              \
    asm("v_permlane32_swap_b32 %0, %1" : "+v"(pq1), "+v"(pq3));              \
    i32x4 tmp_ = {(int)pq0, (int)pq1, (int)pq2, (int)pq3};                   \
    OUT = __builtin_bit_cast(bf16x8, tmp_);                                  \
  }

// ---------------------------------------------------------------------------
// posprep: per node two 16-bf16 vectors so dot(pos1_a, pos2_b) = d2 (hi/lo
// split keeps near-range error ~0.05).
// ---------------------------------------------------------------------------
__global__ __launch_bounds__(256) void posprep_k(
    const float* __restrict__ v, int nNodes, unsigned short* __restrict__ pos1,
    unsigned short* __restrict__ pos2) {
  int i = blockIdx.x * 256 + threadIdx.x;
  if (i >= nNodes) return;
  float x = v[i * 3 + 0], y = v[i * 3 + 1], z = v[i * 3 + 2];
  unsigned short hx = f2bf(x), hy = f2bf(y), hz = f2bf(z);
  float fx = bf2f(hx), fy = bf2f(hy), fz = bf2f(hz);
  unsigned short lx = f2bf(x - fx), ly = f2bf(y - fy), lz = f2bf(z - fz);
  float n = x * x + y * y + z * z;
  unsigned short nh = f2bf(n);
  unsigned short nl = f2bf(n - bf2f(nh));
  unsigned short m2hx = f2bf(-2.f * fx), m2hy = f2bf(-2.f * fy),
                 m2hz = f2bf(-2.f * fz);
  unsigned short m2lx = f2bf(-2.f * bf2f(lx)), m2ly = f2bf(-2.f * bf2f(ly)),
                 m2lz = f2bf(-2.f * bf2f(lz));
  const unsigned short one = 0x3F80;
  u16x8 a0 = {m2hx, m2hy, m2hz, m2lx, m2ly, m2lz, m2hx, m2hy};
  u16x8 a1 = {m2hz, m2lx, m2ly, m2lz, nh, nl, one, one};
  u16x8 b0 = {hx, hy, hz, hx, hy, hz, lx, ly};
  u16x8 b1 = {lz, lx, ly, lz, one, one, nh, nl};
  *(u16x8*)(pos1 + (long)i * 16) = a0;
  *(u16x8*)(pos1 + (long)i * 16 + 8) = a1;
  *(u16x8*)(pos2 + (long)i * 16) = b0;
  *(u16x8*)(pos2 + (long)i * 16 + 8) = b1;
}

// W [K][128] f32 -> Wt [128][K] bf16
__global__ __launch_bounds__(256) void wprep_k(const float* __restrict__ W,
                                               int kshift,
                                               unsigned short* __restrict__ Wt) {
  int idx = blockIdx.x * 256 + threadIdx.x;
  int K = 1 << kshift;
  int e = idx >> kshift, k = idx & (K - 1);
  Wt[(long)e * K + k] = f2bf(W[(long)k * 128 + e]);
}

// ---------------------------------------------------------------------------
// pre GEMM: H = relu(X @ W + b), K=128, bf16 MFMA (16x16x32).
// ---------------------------------------------------------------------------
__global__ __launch_bounds__(256) void pre_mfma_k(
    const float* __restrict__ X, const unsigned short* __restrict__ Wt,
    const float* __restrict__ bias, unsigned short* __restrict__ Hrm) {
  int tid = threadIdx.x, l = tid & 63, w = tid >> 6;
  int g = l >> 4, r = l & 15;
  long row0 = (long)blockIdx.x * 64 + w * 16;
  const float* xrow = X + (row0 + r) * DD;
  f32x4 z4 = {0.f, 0.f, 0.f, 0.f};
  f32x4 acc[8];
#pragma unroll
  for (int i = 0; i < 8; ++i) acc[i] = z4;
#pragma unroll
  for (int ks = 0; ks < 4; ++ks) {
    float4 v0 = *(const float4*)(xrow + ks * 32 + 8 * g);
    float4 v1 = *(const float4*)(xrow + ks * 32 + 8 * g + 4);
    bf16x8 a;
    a[0] = (short)f2bf(v0.x); a[1] = (short)f2bf(v0.y);
    a[2] = (short)f2bf(v0.z); a[3] = (short)f2bf(v0.w);
    a[4] = (short)f2bf(v1.x); a[5] = (short)f2bf(v1.y);
    a[6] = (short)f2bf(v1.z); a[7] = (short)f2bf(v1.w);
#pragma unroll
    for (int ct = 0; ct < 8; ++ct) {
      bf16x8 b = *reinterpret_cast<const bf16x8*>(Wt + (ct * 16 + r) * DD +
                                                  ks * 32 + 8 * g);
      acc[ct] = __builtin_amdgcn_mfma_f32_16x16x32_bf16(a, b, acc[ct], 0, 0, 0);
    }
  }
#pragma unroll
  for (int ct = 0; ct < 8; ++ct) {
    float bv = bias[ct * 16 + r];
#pragma unroll
    for (int r4 = 0; r4 < 4; ++r4) {
      long row = row0 + 4 * g + r4;
      Hrm[row * DD + ct * 16 + r] = f2bf(fmaxf(acc[ct][r4] + bv, 0.f));
    }
  }
}

// bf16 [R][128] -> [128][R]
__global__ __launch_bounds__(256) void transpose_k(
    const unsigned short* __restrict__ H, unsigned short* __restrict__ HT,
    int R) {
  __shared__ unsigned short lds[64 * 136];
  int tid = threadIdx.x;
  long r0 = (long)blockIdx.x * 64;
#pragma unroll
  for (int q = 0; q < 4; ++q) {
    int idx = q * 2048 + tid * 8;
    int rr = idx >> 7, cc = idx & 127;
    *(u16x8*)&lds[rr * 136 + cc] =
        *reinterpret_cast<const u16x8*>(H + (r0 + rr) * 128 + cc);
  }
  __syncthreads();
  int e = tid >> 1, half = tid & 1;
#pragma unroll
  for (int q = 0; q < 4; ++q) {
    u16x8 v;
#pragma unroll
    for (int i = 0; i < 8; ++i)
      v[i] = lds[(half * 32 + q * 8 + i) * 136 + e];
    *reinterpret_cast<u16x8*>(HT + (long)e * R + r0 + half * 32 + q * 8) = v;
  }
}

// ---------------------------------------------------------------------------
// msg_s: block = 128 surface rows (4 waves x 32). Streams Ng in 64-col chunks.
// Swapped pos MFMA (32x32x16): lane&31 = surface row, regs = graph cols.
// w stays in registers -> cvt_pk+permlane -> msg-MFMA A-frags.
// Feature tiles [128][64] in LDS, slot^f&7 swizzle, double-buffered.
// ---------------------------------------------------------------------------
__global__ __launch_bounds__(256) void msg_s_k(
    const unsigned short* __restrict__ pos1_g,
    const unsigned short* __restrict__ pos2_s,
    const unsigned short* __restrict__ xg_hT, unsigned short* __restrict__ xs_o,
    float* __restrict__ l2rs) {
  __shared__ __align__(16) unsigned short ldsB[2][128 * 64];
  const int tid = threadIdx.x;
  const int w = tid >> 6, l = tid & 63;
  const int ln = l & 31, hi = l >> 5;
  const int b = blockIdx.y;
  const long bNS = (long)b * NS, bNG = (long)b * NG;
  const long row0 = (long)blockIdx.x * 128 + w * 32;
  const long BNG = (long)BB * NG;
  const int NCH = NG / 64;

  const bf16x8 bP = *reinterpret_cast<const bf16x8*>(
      pos2_s + (bNS + row0 + ln) * 16 + 8 * hi);

  const f32x16 zz = {0.f, 0.f, 0.f, 0.f, 0.f, 0.f, 0.f, 0.f,
                     0.f, 0.f, 0.f, 0.f, 0.f, 0.f, 0.f, 0.f};
  f32x16 acc[4] = {zz, zz, zz, zz};
  float rs0 = 0.f, rs1 = 0.f, rs2 = 0.f, rs3 = 0.f;

  // staging geometry
  const int tf = tid >> 3;   // 0..31
  const int tsp = tid & 7;   // phys slot
  const int slog8 = (tsp ^ (tf & 7)) * 8;
  const unsigned short* srcb = xg_hT + bNG + slog8;

  u16x8 stA[4];
  bf16x8 pA0, pA1, pA0n, pA1n;
#pragma unroll
  for (int q = 0; q < 4; ++q)
    stA[q] = *reinterpret_cast<const u16x8*>(srcb + (long)(q * 32 + tf) * BNG);
#pragma unroll
  for (int q = 0; q < 4; ++q)
    *(u16x8*)&ldsB[0][(q * 32 + tf) * 64 + tsp * 8] = stA[q];
#pragma unroll
  for (int q = 0; q < 4; ++q)
    stA[q] =
        *reinterpret_cast<const u16x8*>(srcb + (long)(q * 32 + tf) * BNG + 64);
  pA0 = *reinterpret_cast<const bf16x8*>(pos1_g + (bNG + ln) * 16 + 8 * hi);
  pA1 = *reinterpret_cast<const bf16x8*>(pos1_g + (bNG + 32 + ln) * 16 + 8 * hi);
  pA0n = *reinterpret_cast<const bf16x8*>(pos1_g + (bNG + 64 + ln) * 16 + 8 * hi);
  pA1n = *reinterpret_cast<const bf16x8*>(pos1_g + (bNG + 96 + ln) * 16 + 8 * hi);
  __syncthreads();

#pragma unroll 1
  for (int c = 0; c < NCH; ++c) {
    const int buf = c & 1;
    float ex[2][16];
    bf16x8 fr[2][2];
#pragma unroll
    for (int t2 = 0; t2 < 2; ++t2) {
      f32x16 S = __builtin_amdgcn_mfma_f32_32x32x16_bf16(t2 ? pA1 : pA0, bP,
                                                         zz, 0, 0, 0);
#pragma unroll
      for (int r = 0; r < 16; ++r) {
        float d2 = S[r];
        float e = exp2f(d2 * C2);
        ex[t2][r] = (d2 < 64.f) ? e : 0.f;
      }
      PACK_SWAP(ex[t2][0], ex[t2][1], ex[t2][2], ex[t2][3], ex[t2][4],
                ex[t2][5], ex[t2][6], ex[t2][7], fr[t2][0]);
      PACK_SWAP(ex[t2][8], ex[t2][9], ex[t2][10], ex[t2][11], ex[t2][12],
                ex[t2][13], ex[t2][14], ex[t2][15], fr[t2][1]);
    }
#pragma unroll
    for (int r = 0; r < 4; ++r) {
      rs0 += ex[0][r] + ex[1][r];
      rs1 += ex[0][r + 4] + ex[1][r + 4];
      rs2 += ex[0][r + 8] + ex[1][r + 8];
      rs3 += ex[0][r + 12] + ex[1][r + 12];
    }
#pragma unroll
    for (int t2 = 0; t2 < 2; ++t2) {
#pragma unroll
      for (int kh = 0; kh < 2; ++kh) {
        const int kt = t2 * 2 + kh;
        const int spr = ((kt * 2 + hi) ^ (ln & 7)) * 8;
#pragma unroll
        for (int nt = 0; nt < 4; ++nt) {
          const bf16x8 bm = *reinterpret_cast<const bf16x8*>(
              &ldsB[buf][(nt * 32 + ln) * 64 + spr]);
          acc[nt] = __builtin_amdgcn_mfma_f32_32x32x16_bf16(fr[t2][kh], bm,
                                                            acc[nt], 0, 0, 0);
        }
      }
    }
    if (c + 1 < NCH) {
#pragma unroll
      for (int q = 0; q < 4; ++q)
        *(u16x8*)&ldsB[buf ^ 1][(q * 32 + tf) * 64 + tsp * 8] = stA[q];
    }
    if (c + 2 < NCH) {
#pragma unroll
      for (int q = 0; q < 4; ++q)
        stA[q] = *reinterpret_cast<const u16x8*>(
            srcb + (long)(q * 32 + tf) * BNG + (long)(c + 2) * 64);
    }
    pA0 = pA0n;
    pA1 = pA1n;
    if (c + 2 < NCH) {
      pA0n = *reinterpret_cast<const bf16x8*>(
          pos1_g + (bNG + (long)(c + 2) * 64 + ln) * 16 + 8 * hi);
      pA1n = *reinterpret_cast<const bf16x8*>(
          pos1_g + (bNG + (long)(c + 2) * 64 + 32 + ln) * 16 + 8 * hi);
    }
    __syncthreads();
  }

  float rtot = (rs0 + rs1) + (rs2 + rs3);
  rtot += __shfl_xor(rtot, 32, 64);
  float denom = rtot + 1e-8f;
  float rsi = 1.f / denom;
  if (hi == 0) l2rs[bNS + row0 + ln] = -log2f(denom);
#pragma unroll
  for (int r = 0; r < 16; ++r) {
    const int crow = (r & 3) + 8 * (r >> 2) + 4 * hi;
    float rsib = __shfl(rsi, crow, 64);
    long rowg = bNS + row0 + crow;
#pragma unroll
    for (int nt = 0; nt < 4; ++nt)
      xs_o[rowg * DD + nt * 32 + ln] = f2bf(acc[nt][r] * rsib);
  }
}

// ---------------------------------------------------------------------------
// msg_g: block = 128 graph rows (4 waves x 32). Streams its split of Ns.
// w' = exp2(c2*d2 + log2(rsinv[s])) via fused fma; bf16 partials out.
// ---------------------------------------------------------------------------
__global__ __launch_bounds__(256) void msg_g_k(
    const unsigned short* __restrict__ pos1_s,
    const unsigned short* __restrict__ pos2_g,
    const unsigned short* __restrict__ xs_hT, const float* __restrict__ l2rs,
    unsigned short* __restrict__ part) {
  __shared__ __align__(16) unsigned short ldsB[2][128 * 64];
  __shared__ float l2lds[2][64];
  const int tid = threadIdx.x;
  const int w = tid >> 6, l = tid & 63;
  const int ln = l & 31, hi = l >> 5;
  const int b = blockIdx.y, spz = blockIdx.z;
  const long bNS = (long)b * NS, bNG = (long)b * NG;
  const long nbeg = (long)spz * (NS / SPLITG);
  const long row0 = (long)blockIdx.x * 128 + w * 32;
  const long BNS = (long)BB * NS;
  const int NCH = (NS / SPLITG) / 64;

  const bf16x8 bP = *reinterpret_cast<const bf16x8*>(
      pos2_g + (bNG + row0 + ln) * 16 + 8 * hi);

  const f32x16 zz = {0.f, 0.f, 0.f, 0.f, 0.f, 0.f, 0.f, 0.f,
                     0.f, 0.f, 0.f, 0.f, 0.f, 0.f, 0.f, 0.f};
  f32x16 acc[4] = {zz, zz, zz, zz};

  const int tf = tid >> 3;
  const int tsp = tid & 7;
  const int slog8 = (tsp ^ (tf & 7)) * 8;
  const unsigned short* srcb = xs_hT + bNS + nbeg + slog8;

  u16x8 stA[4];
  float stL = 0.f;
  bf16x8 pA0, pA1, pA0n, pA1n;
#pragma unroll
  for (int q = 0; q < 4; ++q)
    stA[q] = *reinterpret_cast<const u16x8*>(srcb + (long)(q * 32 + tf) * BNS);
  if (tid < 64) stL = l2rs[bNS + nbeg + tid];
#pragma unroll
  for (int q = 0; q < 4; ++q)
    *(u16x8*)&ldsB[0][(q * 32 + tf) * 64 + tsp * 8] = stA[q];
  if (tid < 64) l2lds[0][tid] = stL;
#pragma unroll
  for (int q = 0; q < 4; ++q)
    stA[q] =
        *reinterpret_cast<const u16x8*>(srcb + (long)(q * 32 + tf) * BNS + 64);
  if (tid < 64) stL = l2rs[bNS + nbeg + 64 + tid];
  pA0 = *reinterpret_cast<const bf16x8*>(pos1_s + (bNS + nbeg + ln) * 16 + 8 * hi);
  pA1 = *reinterpret_cast<const bf16x8*>(pos1_s +
                                         (bNS + nbeg + 32 + ln) * 16 + 8 * hi);
  pA0n = *reinterpret_cast<const bf16x8*>(pos1_s +
                                          (bNS + nbeg + 64 + ln) * 16 + 8 * hi);
  pA1n = *reinterpret_cast<const bf16x8*>(pos1_s +
                                          (bNS + nbeg + 96 + ln) * 16 + 8 * hi);
  __syncthreads();

#pragma unroll 1
  for (int c = 0; c < NCH; ++c) {
    const int buf = c & 1;
    float ex[2][16];
    bf16x8 fr[2][2];
#pragma unroll
    for (int t2 = 0; t2 < 2; ++t2) {
      f32x16 S = __builtin_amdgcn_mfma_f32_32x32x16_bf16(t2 ? pA1 : pA0, bP,
                                                         zz, 0, 0, 0);
#pragma unroll
      for (int r = 0; r < 16; ++r) {
        float d2 = S[r];
        float lv = l2lds[buf][t2 * 32 + (r & 3) + 8 * (r >> 2) + 4 * hi];
        float e = exp2f(fmaf(d2, C2, lv));
        ex[t2][r] = (d2 < 64.f) ? e : 0.f;
      }
      PACK_SWAP(ex[t2][0], ex[t2][1], ex[t2][2], ex[t2][3], ex[t2][4],
                ex[t2][5], ex[t2][6], ex[t2][7], fr[t2][0]);
      PACK_SWAP(ex[t2][8], ex[t2][9], ex[t2][10], ex[t2][11], ex[t2][12],
                ex[t2][13], ex[t2][14], ex[t2][15], fr[t2][1]);
    }
#pragma unroll
    for (int t2 = 0; t2 < 2; ++t2) {
#pragma unroll
      for (int kh = 0; kh < 2; ++kh) {
        const int kt = t2 * 2 + kh;
        const int spr = ((kt * 2 + hi) ^ (ln & 7)) * 8;
#pragma unroll
        for (int nt = 0; nt < 4; ++nt) {
          const bf16x8 bm = *reinterpret_cast<const bf16x8*>(
              &ldsB[buf][(nt * 32 + ln) * 64 + spr]);
          acc[nt] = __builtin_amdgcn_mfma_f32_32x32x16_bf16(fr[t2][kh], bm,
                                                            acc[nt], 0, 0, 0);
        }
      }
    }
    if (c + 1 < NCH) {
#pragma unroll
      for (int q = 0; q < 4; ++q)
        *(u16x8*)&ldsB[buf ^ 1][(q * 32 + tf) * 64 + tsp * 8] = stA[q];
      if (tid < 64) l2lds[buf ^ 1][tid] = stL;
    }
    if (c + 2 < NCH) {
#pragma unroll
      for (int q = 0; q < 4; ++q)
        stA[q] = *reinterpret_cast<const u16x8*>(
            srcb + (long)(q * 32 + tf) * BNS + (long)(c + 2) * 64);
      if (tid < 64) stL = l2rs[bNS + nbeg + (long)(c + 2) * 64 + tid];
    }
    pA0 = pA0n;
    pA1 = pA1n;
    if (c + 2 < NCH) {
      pA0n = *reinterpret_cast<const bf16x8*>(
          pos1_s + (bNS + nbeg + (long)(c + 2) * 64 + ln) * 16 + 8 * hi);
      pA1n = *reinterpret_cast<const bf16x8*>(
          pos1_s + (bNS + nbeg + (long)(c + 2) * 64 + 32 + ln) * 16 + 8 * hi);
    }
    __syncthreads();
  }

  const long pbase = (long)spz * BB * NG;
#pragma unroll
  for (int r = 0; r < 16; ++r) {
    const int crow = (r & 3) + 8 * (r >> 2) + 4 * hi;
    long rowg = pbase + bNG + row0 + crow;
#pragma unroll
    for (int nt = 0; nt < 4; ++nt)
      part[rowg * DD + nt * 32 + ln] = f2bf(acc[nt][r]);
  }
}

__global__ __launch_bounds__(256) void reduce_k(
    const unsigned short* __restrict__ part, unsigned short* __restrict__ xg_o) {
  long i = ((long)blockIdx.x * 256 + threadIdx.x) * 8;
  const long S = (long)BB * NG * DD;
  float a[8];
#pragma unroll
  for (int k = 0; k < 8; ++k) a[k] = 0.f;
#pragma unroll
  for (int s = 0; s < SPLITG; ++s) {
    u16x8 v = *reinterpret_cast<const u16x8*>(part + s * S + i);
#pragma unroll
    for (int k = 0; k < 8; ++k) a[k] += bf2f(v[k]);
  }
  u16x8 o;
#pragma unroll
  for (int k = 0; k < 8; ++k) o[k] = f2bf(a[k]);
  *reinterpret_cast<u16x8*>(xg_o + i) = o;
}

// ---------------------------------------------------------------------------
// post GEMM: out = relu([Ha|Hb] @ W + b), K=256, f32 output.
// ---------------------------------------------------------------------------
__global__ __launch_bounds__(256) void post_mfma_k(
    const unsigned short* __restrict__ Ha, const unsigned short* __restrict__ Hb,
    const unsigned short* __restrict__ Wt, const float* __restrict__ bias,
    float* __restrict__ out, int shift, int mask, int off) {
  int tid = threadIdx.x, l = tid & 63, w = tid >> 6;
  int g = l >> 4, r = l & 15;
  long row0 = (long)blockIdx.x * 64 + w * 16;
  const unsigned short* ha = Ha + (row0 + r) * DD;
  const unsigned short* hb = Hb + (row0 + r) * DD;
  f32x4 z4 = {0.f, 0.f, 0.f, 0.f};
  f32x4 acc[8];
#pragma unroll
  for (int i = 0; i < 8; ++i) acc[i] = z4;
#pragma unroll
  for (int ks = 0; ks < 8; ++ks) {
    const unsigned short* src = (ks < 4) ? (ha + ks * 32) : (hb + (ks - 4) * 32);
    bf16x8 a = *reinterpret_cast<const bf16x8*>(src + 8 * g);
#pragma unroll
    for (int ct = 0; ct < 8; ++ct) {
      bf16x8 b = *reinterpret_cast<const bf16x8*>(Wt + (ct * 16 + r) * 256 +
                                                  ks * 32 + 8 * g);
      acc[ct] = __builtin_amdgcn_mfma_f32_16x16x32_bf16(a, b, acc[ct], 0, 0, 0);
    }
  }
#pragma unroll
  for (int ct = 0; ct < 8; ++ct) {
    float bv = bias[ct * 16 + r];
#pragma unroll
    for (int r4 = 0; r4 < 4; ++r4) {
      long rowg = row0 + 4 * g + r4;
      long bb = rowg >> shift;
      long n = rowg & mask;
      out[(bb * (NS + NG) + off + n) * DD + ct * 16 + r] =
          fmaxf(acc[ct][r4] + bv, 0.f);
    }
  }
}

// ---------------------------------------------------------------------------
extern "C" void kernel_launch(void* const* d_in, const int* in_sizes, int n_in,
                              void* d_out, int out_size, void* d_ws,
                              size_t ws_size, hipStream_t stream) {
  const float* xs = (const float*)d_in[0];
  const float* xg = (const float*)d_in[1];
  const float* vs = (const float*)d_in[2];
  const float* vg = (const float*)d_in[3];
  const float* Ws_pre = (const float*)d_in[4];
  const float* bs_pre = (const float*)d_in[5];
  const float* Wg_pre = (const float*)d_in[6];
  const float* bg_pre = (const float*)d_in[7];
  const float* Ws_post = (const float*)d_in[8];
  const float* bs_post = (const float*)d_in[9];
  const float* Wg_post = (const float*)d_in[10];
  const float* bg_post = (const float*)d_in[11];
  float* out = (float*)d_out;

  char* p = (char*)d_ws;
  unsigned short* pos1_s = (unsigned short*)p; p += (size_t)BB * NS * 16 * 2;
  unsigned short* pos2_s = (unsigned short*)p; p += (size_t)BB * NS * 16 * 2;
  unsigned short* pos1_g = (unsigned short*)p; p += (size_t)BB * NG * 16 * 2;
  unsigned short* pos2_g = (unsigned short*)p; p += (size_t)BB * NG * 16 * 2;
  unsigned short* WtS_pre = (unsigned short*)p; p += (size_t)128 * 128 * 2;
  unsigned short* WtG_pre = (unsigned short*)p; p += (size_t)128 * 128 * 2;
  unsigned short* WtS_post = (unsigned short*)p; p += (size_t)128 * 256 * 2;
  unsigned short* WtG_post = (unsigned short*)p; p += (size_t)128 * 256 * 2;
  unsigned short* xs_h = (unsigned short*)p; p += (size_t)BB * NS * DD * 2;
  unsigned short* xg_h = (unsigned short*)p; p += (size_t)BB * NG * DD * 2;
  unsigned short* xs_hT = (unsigned short*)p; p += (size_t)BB * NS * DD * 2;
  unsigned short* xg_hT = (unsigned short*)p; p += (size_t)BB * NG * DD * 2;
  unsigned short* xs_o = (unsigned short*)p; p += (size_t)BB * NS * DD * 2;
  unsigned short* xg_o = (unsigned short*)p; p += (size_t)BB * NG * DD * 2;
  float* l2rs = (float*)p; p += (size_t)BB * NS * 4;
  unsigned short* part = (unsigned short*)p;
  p += (size_t)SPLITG * BB * NG * DD * 2;

  posprep_k<<<(BB * NS) / 256, 256, 0, stream>>>(vs, BB * NS, pos1_s, pos2_s);
  posprep_k<<<(BB * NG) / 256, 256, 0, stream>>>(vg, BB * NG, pos1_g, pos2_g);
  wprep_k<<<64, 256, 0, stream>>>(Ws_pre, 7, WtS_pre);
  wprep_k<<<64, 256, 0, stream>>>(Wg_pre, 7, WtG_pre);
  wprep_k<<<128, 256, 0, stream>>>(Ws_post, 8, WtS_post);
  wprep_k<<<128, 256, 0, stream>>>(Wg_post, 8, WtG_post);
  pre_mfma_k<<<BB * NS / 64, 256, 0, stream>>>(xs, WtS_pre, bs_pre, xs_h);
  pre_mfma_k<<<BB * NG / 64, 256, 0, stream>>>(xg, WtG_pre, bg_pre, xg_h);
  transpose_k<<<BB * NS / 64, 256, 0, stream>>>(xs_h, xs_hT, BB * NS);
  transpose_k<<<BB * NG / 64, 256, 0, stream>>>(xg_h, xg_hT, BB * NG);
  msg_s_k<<<dim3(NS / 128, BB), 256, 0, stream>>>(pos1_g, pos2_s, xg_hT, xs_o,
                                                  l2rs);
  msg_g_k<<<dim3(NG / 128, BB, SPLITG), 256, 0, stream>>>(pos1_s, pos2_g,
                                                          xs_hT, l2rs, part);
  reduce_k<<<(BB * NG * DD) / 8 / 256, 256, 0, stream>>>(part, xg_o);
  post_mfma_k<<<BB * NS / 64, 256, 0, stream>>>(xs_h, xs_o, WtS_post, bs_post,
                                                out, 14, NS - 1, 0);
  post_mfma_k<<<BB * NG / 64, 256, 0, stream>>>(xg_h, xg_o, WtG_post, bg_post,
                                                out, 11, NG - 1, NS);
}

// Round 4
// 198.395 us; speedup vs baseline: 13.1666x; 1.3768x over previous
//
#include <hip/hip_runtime.h>
#include <hip/hip_bf16.h>

#define BB 4
#define NS 16384
#define NG 2048
#define DD 128
#define SPLITG 16
#define C2 (-0.23083120f)  // -log2(e)/sigma^2

typedef short bf16x8 __attribute__((ext_vector_type(8)));
typedef unsigned short u16x8 __attribute__((ext_vector_type(8)));
typedef float f32x4 __attribute__((ext_vector_type(4)));
typedef float f32x16 __attribute__((ext_vector_type(16)));
typedef int i32x4 __attribute__((ext_vector_type(4)));

#if __has_builtin(__builtin_amdgcn_exp2f)
#define EXP2(x) __builtin_amdgcn_exp2f(x)
#else
#define EXP2(x) exp2f(x)
#endif

__device__ __forceinline__ unsigned short f2bf(float x) {
  unsigned int u = __builtin_bit_cast(unsigned int, x);
  u += 0x7FFFu + ((u >> 16) & 1u);
  return (unsigned short)(u >> 16);
}
__device__ __forceinline__ float bf2f(unsigned short h) {
  unsigned int u = ((unsigned int)h) << 16;
  return __builtin_bit_cast(float, u);
}

// pack 8 f32 -> bf16x8 A-fragment via cvt_pk + permlane32_swap (T12 recipe)
#define PACK_SWAP(e0, e1, e2, e3, e4, e5, e6, e7, OUT)                       \
  {                                                                          \
    unsigned pq0, pq1, pq2, pq3;                                             \
    asm("v_cvt_pk_bf16_f32 %0, %1, %2" : "=v"(pq0) : "v"(e0), "v"(e1));      \
    asm("v_cvt_pk_bf16_f32 %0, %1, %2" : "=v"(pq1) : "v"(e2), "v"(e3));      \
    asm("v_cvt_pk_bf16_f32 %0, %1, %2" : "=v"(pq2) : "v"(e4), "v"(e5));      \
    asm("v_cvt_pk_bf16_f32 %0, %1, %2" : "=v"(pq3) : "v"(e6), "v"(e7));      \
    asm("v_permlane32_swap_b32 %0, %1" : "+v"(pq0), "+v"(pq2));              \
    asm("v_permlane32_swap_b32 %0, %1" : "+v"(pq1), "+v"(pq3));              \
    i32x4 tmp_ = {(int)pq0, (int)pq1, (int)pq2, (int)pq3};                   \
    OUT = __builtin_bit_cast(bf16x8, tmp_);                                  \
  }

// ---------------------------------------------------------------------------
// prep: node pos encodings (dot(pos1,pos2)=d2, hi/lo split) + weight
// transposes, all fused into one launch.
// ---------------------------------------------------------------------------
__device__ __forceinline__ void posprep1(const float* __restrict__ v, int i,
                                         unsigned short* __restrict__ pos1,
                                         unsigned short* __restrict__ pos2) {
  float x = v[i * 3 + 0], y = v[i * 3 + 1], z = v[i * 3 + 2];
  unsigned short hx = f2bf(x), hy = f2bf(y), hz = f2bf(z);
  float fx = bf2f(hx), fy = bf2f(hy), fz = bf2f(hz);
  unsigned short lx = f2bf(x - fx), ly = f2bf(y - fy), lz = f2bf(z - fz);
  float n = x * x + y * y + z * z;
  unsigned short nh = f2bf(n);
  unsigned short nl = f2bf(n - bf2f(nh));
  unsigned short m2hx = f2bf(-2.f * fx), m2hy = f2bf(-2.f * fy),
                 m2hz = f2bf(-2.f * fz);
  unsigned short m2lx = f2bf(-2.f * bf2f(lx)), m2ly = f2bf(-2.f * bf2f(ly)),
                 m2lz = f2bf(-2.f * bf2f(lz));
  const unsigned short one = 0x3F80;
  u16x8 a0 = {m2hx, m2hy, m2hz, m2lx, m2ly, m2lz, m2hx, m2hy};
  u16x8 a1 = {m2hz, m2lx, m2ly, m2lz, nh, nl, one, one};
  u16x8 b0 = {hx, hy, hz, hx, hy, hz, lx, ly};
  u16x8 b1 = {lz, lx, ly, lz, one, one, nh, nl};
  *(u16x8*)(pos1 + (long)i * 16) = a0;
  *(u16x8*)(pos1 + (long)i * 16 + 8) = a1;
  *(u16x8*)(pos2 + (long)i * 16) = b0;
  *(u16x8*)(pos2 + (long)i * 16 + 8) = b1;
}

__global__ __launch_bounds__(256) void prep_k(
    const float* __restrict__ vs, const float* __restrict__ vg,
    const float* __restrict__ Ws_pre, const float* __restrict__ Wg_pre,
    const float* __restrict__ Ws_post, const float* __restrict__ Wg_post,
    unsigned short* __restrict__ pos1_s, unsigned short* __restrict__ pos2_s,
    unsigned short* __restrict__ pos1_g, unsigned short* __restrict__ pos2_g,
    unsigned short* __restrict__ WtS_pre, unsigned short* __restrict__ WtG_pre,
    unsigned short* __restrict__ WtS_post,
    unsigned short* __restrict__ WtG_post) {
  const int NODEBLK = (BB * (NS + NG)) / 256;  // 288
  int bid = blockIdx.x, tid = threadIdx.x;
  if (bid < NODEBLK) {
    int i = bid * 256 + tid;
    if (i < BB * NS)
      posprep1(vs, i, pos1_s, pos2_s);
    else
      posprep1(vg, i - BB * NS, pos1_g, pos2_g);
  } else {
    int k2 = (bid - NODEBLK) * 256 + tid;
    const float* W;
    unsigned short* Wt;
    int kshift, loc;
    if (k2 < 16384) { W = Ws_pre; Wt = WtS_pre; kshift = 7; loc = k2; }
    else if (k2 < 32768) { W = Wg_pre; Wt = WtG_pre; kshift = 7; loc = k2 - 16384; }
    else if (k2 < 65536) { W = Ws_post; Wt = WtS_post; kshift = 8; loc = k2 - 32768; }
    else { W = Wg_post; Wt = WtG_post; kshift = 8; loc = k2 - 65536; }
    int K = 1 << kshift;
    int e = loc >> kshift, k = loc & (K - 1);
    Wt[(long)e * K + k] = f2bf(W[(long)k * 128 + e]);
  }
}

// ---------------------------------------------------------------------------
// pre GEMM (surface + graph fused): H = relu(X @ W + b), K=128.
// ---------------------------------------------------------------------------
__global__ __launch_bounds__(256) void pre_mfma_k(
    const float* __restrict__ xs, const float* __restrict__ xg,
    const unsigned short* __restrict__ WtS,
    const unsigned short* __restrict__ WtG, const float* __restrict__ bs,
    const float* __restrict__ bg, unsigned short* __restrict__ xs_h,
    unsigned short* __restrict__ xg_h) {
  long r0 = (long)blockIdx.x * 64;
  const float* X;
  const unsigned short* Wt;
  const float* bias;
  unsigned short* H;
  long row0;
  if (r0 < (long)BB * NS) {
    X = xs; Wt = WtS; bias = bs; H = xs_h; row0 = r0;
  } else {
    X = xg; Wt = WtG; bias = bg; H = xg_h; row0 = r0 - (long)BB * NS;
  }
  int tid = threadIdx.x, l = tid & 63, w = tid >> 6;
  int g = l >> 4, r = l & 15;
  row0 += w * 16;
  const float* xrow = X + (row0 + r) * DD;
  f32x4 z4 = {0.f, 0.f, 0.f, 0.f};
  f32x4 acc[8];
#pragma unroll
  for (int i = 0; i < 8; ++i) acc[i] = z4;
#pragma unroll
  for (int ks = 0; ks < 4; ++ks) {
    float4 v0 = *(const float4*)(xrow + ks * 32 + 8 * g);
    float4 v1 = *(const float4*)(xrow + ks * 32 + 8 * g + 4);
    bf16x8 a;
    a[0] = (short)f2bf(v0.x); a[1] = (short)f2bf(v0.y);
    a[2] = (short)f2bf(v0.z); a[3] = (short)f2bf(v0.w);
    a[4] = (short)f2bf(v1.x); a[5] = (short)f2bf(v1.y);
    a[6] = (short)f2bf(v1.z); a[7] = (short)f2bf(v1.w);
#pragma unroll
    for (int ct = 0; ct < 8; ++ct) {
      bf16x8 b = *reinterpret_cast<const bf16x8*>(Wt + (ct * 16 + r) * DD +
                                                  ks * 32 + 8 * g);
      acc[ct] = __builtin_amdgcn_mfma_f32_16x16x32_bf16(a, b, acc[ct], 0, 0, 0);
    }
  }
#pragma unroll
  for (int ct = 0; ct < 8; ++ct) {
    float bv = bias[ct * 16 + r];
#pragma unroll
    for (int r4 = 0; r4 < 4; ++r4) {
      long row = row0 + 4 * g + r4;
      H[row * DD + ct * 16 + r] = f2bf(fmaxf(acc[ct][r4] + bv, 0.f));
    }
  }
}

// ---------------------------------------------------------------------------
// bf16 [R][128] -> [128][R], optional per-row scale (rsinv fold for msg_g)
// ---------------------------------------------------------------------------
__global__ __launch_bounds__(256) void transpose_k(
    const unsigned short* __restrict__ H, unsigned short* __restrict__ HT,
    int R, const float* __restrict__ scale) {
  __shared__ unsigned short lds[64 * 136];
  int tid = threadIdx.x;
  long r0 = (long)blockIdx.x * 64;
#pragma unroll
  for (int q = 0; q < 4; ++q) {
    int idx = q * 2048 + tid * 8;
    int rr = idx >> 7, cc = idx & 127;
    u16x8 v = *reinterpret_cast<const u16x8*>(H + (r0 + rr) * 128 + cc);
    if (scale) {
      float s = scale[r0 + rr];
#pragma unroll
      for (int i = 0; i < 8; ++i) v[i] = f2bf(bf2f(v[i]) * s);
    }
    *(u16x8*)&lds[rr * 136 + cc] = v;
  }
  __syncthreads();
  int e = tid >> 1, half = tid & 1;
#pragma unroll
  for (int q = 0; q < 4; ++q) {
    u16x8 v;
#pragma unroll
    for (int i = 0; i < 8; ++i)
      v[i] = lds[(half * 32 + q * 8 + i) * 136 + e];
    *reinterpret_cast<u16x8*>(HT + (long)e * R + r0 + half * 32 + q * 8) = v;
  }
}

// ---------------------------------------------------------------------------
// msg_s: block = 128 surface rows (4 waves x 32). Streams Ng in 64-col chunks.
// Swapped pos MFMA (32x32x16) -> d2 in regs -> raw v_exp -> cvt_pk+permlane
// -> msg MFMA A-frags. Features [128][64] in LDS, slot^f&7 swizzle, dbuf.
// ---------------------------------------------------------------------------
__global__ __launch_bounds__(256) void msg_s_k(
    const unsigned short* __restrict__ pos1_g,
    const unsigned short* __restrict__ pos2_s,
    const unsigned short* __restrict__ xg_hT, unsigned short* __restrict__ xs_o,
    float* __restrict__ rsinv) {
  __shared__ __align__(16) unsigned short ldsB[2][128 * 64];
  const int tid = threadIdx.x;
  const int w = tid >> 6, l = tid & 63;
  const int ln = l & 31, hi = l >> 5;
  const int b = blockIdx.y;
  const long bNS = (long)b * NS, bNG = (long)b * NG;
  const long row0 = (long)blockIdx.x * 128 + w * 32;
  const long BNG = (long)BB * NG;
  const int NCH = NG / 64;

  const bf16x8 bP = *reinterpret_cast<const bf16x8*>(
      pos2_s + (bNS + row0 + ln) * 16 + 8 * hi);

  const f32x16 zz = {0.f, 0.f, 0.f, 0.f, 0.f, 0.f, 0.f, 0.f,
                     0.f, 0.f, 0.f, 0.f, 0.f, 0.f, 0.f, 0.f};
  f32x16 acc[4] = {zz, zz, zz, zz};
  float rs0 = 0.f, rs1 = 0.f, rs2 = 0.f, rs3 = 0.f;

  const int tf = tid >> 3;
  const int tsp = tid & 7;
  // hoisted staging pointers (advance 64 elems/chunk)
  const unsigned short* p0 = xg_hT + (long)(0 * 32 + tf) * BNG + bNG +
                             (tsp ^ (tf & 7)) * 8;
  const unsigned short* p1 = p0 + (long)32 * BNG;
  const unsigned short* p2 = p0 + (long)64 * BNG;
  const unsigned short* p3 = p0 + (long)96 * BNG;
  const unsigned short* pp = pos1_g + (bNG + ln) * 16 + 8 * hi;

  u16x8 stA[4];
  bf16x8 pA0, pA1, pA0n, pA1n;
  stA[0] = *reinterpret_cast<const u16x8*>(p0);
  stA[1] = *reinterpret_cast<const u16x8*>(p1);
  stA[2] = *reinterpret_cast<const u16x8*>(p2);
  stA[3] = *reinterpret_cast<const u16x8*>(p3);
#pragma unroll
  for (int q = 0; q < 4; ++q)
    *(u16x8*)&ldsB[0][(q * 32 + tf) * 64 + tsp * 8] = stA[q];
  stA[0] = *reinterpret_cast<const u16x8*>(p0 + 64);
  stA[1] = *reinterpret_cast<const u16x8*>(p1 + 64);
  stA[2] = *reinterpret_cast<const u16x8*>(p2 + 64);
  stA[3] = *reinterpret_cast<const u16x8*>(p3 + 64);
  p0 += 128; p1 += 128; p2 += 128; p3 += 128;
  pA0 = *reinterpret_cast<const bf16x8*>(pp);
  pA1 = *reinterpret_cast<const bf16x8*>(pp + 32 * 16);
  pA0n = *reinterpret_cast<const bf16x8*>(pp + 64 * 16);
  pA1n = *reinterpret_cast<const bf16x8*>(pp + 96 * 16);
  pp += 128 * 16;
  __syncthreads();

#pragma unroll 1
  for (int c = 0; c < NCH; ++c) {
    const int buf = c & 1;
    float ex[2][16];
    bf16x8 fr[2][2];
#pragma unroll
    for (int t2 = 0; t2 < 2; ++t2) {
      f32x16 S = __builtin_amdgcn_mfma_f32_32x32x16_bf16(t2 ? pA1 : pA0, bP,
                                                         zz, 0, 0, 0);
#pragma unroll
      for (int r = 0; r < 16; ++r) ex[t2][r] = EXP2(S[r] * C2);
      PACK_SWAP(ex[t2][0], ex[t2][1], ex[t2][2], ex[t2][3], ex[t2][4],
                ex[t2][5], ex[t2][6], ex[t2][7], fr[t2][0]);
      PACK_SWAP(ex[t2][8], ex[t2][9], ex[t2][10], ex[t2][11], ex[t2][12],
                ex[t2][13], ex[t2][14], ex[t2][15], fr[t2][1]);
    }
#pragma unroll
    for (int r = 0; r < 4; ++r) {
      rs0 += ex[0][r] + ex[1][r];
      rs1 += ex[0][r + 4] + ex[1][r + 4];
      rs2 += ex[0][r + 8] + ex[1][r + 8];
      rs3 += ex[0][r + 12] + ex[1][r + 12];
    }
#pragma unroll
    for (int t2 = 0; t2 < 2; ++t2) {
#pragma unroll
      for (int kh = 0; kh < 2; ++kh) {
        const int kt = t2 * 2 + kh;
        const int spr = ((kt * 2 + hi) ^ (ln & 7)) * 8;
#pragma unroll
        for (int nt = 0; nt < 4; ++nt) {
          const bf16x8 bm = *reinterpret_cast<const bf16x8*>(
              &ldsB[buf][(nt * 32 + ln) * 64 + spr]);
          acc[nt] = __builtin_amdgcn_mfma_f32_32x32x16_bf16(fr[t2][kh], bm,
                                                            acc[nt], 0, 0, 0);
        }
      }
    }
    if (c + 1 < NCH) {
#pragma unroll
      for (int q = 0; q < 4; ++q)
        *(u16x8*)&ldsB[buf ^ 1][(q * 32 + tf) * 64 + tsp * 8] = stA[q];
    }
    if (c + 2 < NCH) {
      stA[0] = *reinterpret_cast<const u16x8*>(p0);
      stA[1] = *reinterpret_cast<const u16x8*>(p1);
      stA[2] = *reinterpret_cast<const u16x8*>(p2);
      stA[3] = *reinterpret_cast<const u16x8*>(p3);
      p0 += 64; p1 += 64; p2 += 64; p3 += 64;
    }
    pA0 = pA0n;
    pA1 = pA1n;
    if (c + 2 < NCH) {
      pA0n = *reinterpret_cast<const bf16x8*>(pp);
      pA1n = *reinterpret_cast<const bf16x8*>(pp + 32 * 16);
      pp += 64 * 16;
    }
    __syncthreads();
  }

  float rtot = (rs0 + rs1) + (rs2 + rs3);
  rtot += __shfl_xor(rtot, 32, 64);
  float denom = rtot + 1e-8f;
  float rsi = 1.f / denom;
  if (hi == 0) rsinv[bNS + row0 + ln] = rsi;
#pragma unroll
  for (int r = 0; r < 16; ++r) {
    const int crow = (r & 3) + 8 * (r >> 2) + 4 * hi;
    float rsib = __shfl(rsi, crow, 64);
    long rowg = bNS + row0 + crow;
#pragma unroll
    for (int nt = 0; nt < 4; ++nt)
      xs_o[rowg * DD + nt * 32 + ln] = f2bf(acc[nt][r] * rsib);
  }
}

// ---------------------------------------------------------------------------
// msg_g: block = 128 graph rows (4 waves x 32). Streams its 1/SPLITG of Ns.
// xs_hT is pre-scaled by rsinv, so no per-element normalization here.
// ---------------------------------------------------------------------------
__global__ __launch_bounds__(256) void msg_g_k(
    const unsigned short* __restrict__ pos1_s,
    const unsigned short* __restrict__ pos2_g,
    const unsigned short* __restrict__ xs_hT, unsigned short* __restrict__ part) {
  __shared__ __align__(16) unsigned short ldsB[2][128 * 64];
  const int tid = threadIdx.x;
  const int w = tid >> 6, l = tid & 63;
  const int ln = l & 31, hi = l >> 5;
  const int b = blockIdx.y, spz = blockIdx.z;
  const long bNS = (long)b * NS, bNG = (long)b * NG;
  const long nbeg = (long)spz * (NS / SPLITG);
  const long row0 = (long)blockIdx.x * 128 + w * 32;
  const long BNS = (long)BB * NS;
  const int NCH = (NS / SPLITG) / 64;

  const bf16x8 bP = *reinterpret_cast<const bf16x8*>(
      pos2_g + (bNG + row0 + ln) * 16 + 8 * hi);

  const f32x16 zz = {0.f, 0.f, 0.f, 0.f, 0.f, 0.f, 0.f, 0.f,
                     0.f, 0.f, 0.f, 0.f, 0.f, 0.f, 0.f, 0.f};
  f32x16 acc[4] = {zz, zz, zz, zz};

  const int tf = tid >> 3;
  const int tsp = tid & 7;
  const unsigned short* p0 = xs_hT + (long)(0 * 32 + tf) * BNS + bNS + nbeg +
                             (tsp ^ (tf & 7)) * 8;
  const unsigned short* p1 = p0 + (long)32 * BNS;
  const unsigned short* p2 = p0 + (long)64 * BNS;
  const unsigned short* p3 = p0 + (long)96 * BNS;
  const unsigned short* pp = pos1_s + (bNS + nbeg + ln) * 16 + 8 * hi;

  u16x8 stA[4];
  bf16x8 pA0, pA1, pA0n, pA1n;
  stA[0] = *reinterpret_cast<const u16x8*>(p0);
  stA[1] = *reinterpret_cast<const u16x8*>(p1);
  stA[2] = *reinterpret_cast<const u16x8*>(p2);
  stA[3] = *reinterpret_cast<const u16x8*>(p3);
#pragma unroll
  for (int q = 0; q < 4; ++q)
    *(u16x8*)&ldsB[0][(q * 32 + tf) * 64 + tsp * 8] = stA[q];
  stA[0] = *reinterpret_cast<const u16x8*>(p0 + 64);
  stA[1] = *reinterpret_cast<const u16x8*>(p1 + 64);
  stA[2] = *reinterpret_cast<const u16x8*>(p2 + 64);
  stA[3] = *reinterpret_cast<const u16x8*>(p3 + 64);
  p0 += 128; p1 += 128; p2 += 128; p3 += 128;
  pA0 = *reinterpret_cast<const bf16x8*>(pp);
  pA1 = *reinterpret_cast<const bf16x8*>(pp + 32 * 16);
  pA0n = *reinterpret_cast<const bf16x8*>(pp + 64 * 16);
  pA1n = *reinterpret_cast<const bf16x8*>(pp + 96 * 16);
  pp += 128 * 16;
  __syncthreads();

#pragma unroll 1
  for (int c = 0; c < NCH; ++c) {
    const int buf = c & 1;
    float ex[2][16];
    bf16x8 fr[2][2];
#pragma unroll
    for (int t2 = 0; t2 < 2; ++t2) {
      f32x16 S = __builtin_amdgcn_mfma_f32_32x32x16_bf16(t2 ? pA1 : pA0, bP,
                                                         zz, 0, 0, 0);
#pragma unroll
      for (int r = 0; r < 16; ++r) ex[t2][r] = EXP2(S[r] * C2);
      PACK_SWAP(ex[t2][0], ex[t2][1], ex[t2][2], ex[t2][3], ex[t2][4],
                ex[t2][5], ex[t2][6], ex[t2][7], fr[t2][0]);
      PACK_SWAP(ex[t2][8], ex[t2][9], ex[t2][10], ex[t2][11], ex[t2][12],
                ex[t2][13], ex[t2][14], ex[t2][15], fr[t2][1]);
    }
#pragma unroll
    for (int t2 = 0; t2 < 2; ++t2) {
#pragma unroll
      for (int kh = 0; kh < 2; ++kh) {
        const int kt = t2 * 2 + kh;
        const int spr = ((kt * 2 + hi) ^ (ln & 7)) * 8;
#pragma unroll
        for (int nt = 0; nt < 4; ++nt) {
          const bf16x8 bm = *reinterpret_cast<const bf16x8*>(
              &ldsB[buf][(nt * 32 + ln) * 64 + spr]);
          acc[nt] = __builtin_amdgcn_mfma_f32_32x32x16_bf16(fr[t2][kh], bm,
                                                            acc[nt], 0, 0, 0);
        }
      }
    }
    if (c + 1 < NCH) {
#pragma unroll
      for (int q = 0; q < 4; ++q)
        *(u16x8*)&ldsB[buf ^ 1][(q * 32 + tf) * 64 + tsp * 8] = stA[q];
    }
    if (c + 2 < NCH) {
      stA[0] = *reinterpret_cast<const u16x8*>(p0);
      stA[1] = *reinterpret_cast<const u16x8*>(p1);
      stA[2] = *reinterpret_cast<const u16x8*>(p2);
      stA[3] = *reinterpret_cast<const u16x8*>(p3);
      p0 += 64; p1 += 64; p2 += 64; p3 += 64;
    }
    pA0 = pA0n;
    pA1 = pA1n;
    if (c + 2 < NCH) {
      pA0n = *reinterpret_cast<const bf16x8*>(pp);
      pA1n = *reinterpret_cast<const bf16x8*>(pp + 32 * 16);
      pp += 64 * 16;
    }
    __syncthreads();
  }

  const long pbase = (long)spz * BB * NG;
#pragma unroll
  for (int r = 0; r < 16; ++r) {
    const int crow = (r & 3) + 8 * (r >> 2) + 4 * hi;
    long rowg = pbase + bNG + row0 + crow;
#pragma unroll
    for (int nt = 0; nt < 4; ++nt)
      part[rowg * DD + nt * 32 + ln] = f2bf(acc[nt][r]);
  }
}

__global__ __launch_bounds__(256) void reduce_k(
    const unsigned short* __restrict__ part, unsigned short* __restrict__ xg_o) {
  long i = ((long)blockIdx.x * 256 + threadIdx.x) * 8;
  const long S = (long)BB * NG * DD;
  float a[8];
#pragma unroll
  for (int k = 0; k < 8; ++k) a[k] = 0.f;
#pragma unroll
  for (int s = 0; s < SPLITG; ++s) {
    u16x8 v = *reinterpret_cast<const u16x8*>(part + s * S + i);
#pragma unroll
    for (int k = 0; k < 8; ++k) a[k] += bf2f(v[k]);
  }
  u16x8 o;
#pragma unroll
  for (int k = 0; k < 8; ++k) o[k] = f2bf(a[k]);
  *reinterpret_cast<u16x8*>(xg_o + i) = o;
}

// ---------------------------------------------------------------------------
// post GEMM: out = relu([Ha|Hb] @ W + b), K=256, f32 output.
// ---------------------------------------------------------------------------
__global__ __launch_bounds__(256) void post_mfma_k(
    const unsigned short* __restrict__ Ha, const unsigned short* __restrict__ Hb,
    const unsigned short* __restrict__ Wt, const float* __restrict__ bias,
    float* __restrict__ out, int shift, int mask, int off) {
  int tid = threadIdx.x, l = tid & 63, w = tid >> 6;
  int g = l >> 4, r = l & 15;
  long row0 = (long)blockIdx.x * 64 + w * 16;
  const unsigned short* ha = Ha + (row0 + r) * DD;
  const unsigned short* hb = Hb + (row0 + r) * DD;
  f32x4 z4 = {0.f, 0.f, 0.f, 0.f};
  f32x4 acc[8];
#pragma unroll
  for (int i = 0; i < 8; ++i) acc[i] = z4;
#pragma unroll
  for (int ks = 0; ks < 8; ++ks) {
    const unsigned short* src = (ks < 4) ? (ha + ks * 32) : (hb + (ks - 4) * 32);
    bf16x8 a = *reinterpret_cast<const bf16x8*>(src + 8 * g);
#pragma unroll
    for (int ct = 0; ct < 8; ++ct) {
      bf16x8 b = *reinterpret_cast<const bf16x8*>(Wt + (ct * 16 + r) * 256 +
                                                  ks * 32 + 8 * g);
      acc[ct] = __builtin_amdgcn_mfma_f32_16x16x32_bf16(a, b, acc[ct], 0, 0, 0);
    }
  }
#pragma unroll
  for (int ct = 0; ct < 8; ++ct) {
    float bv = bias[ct * 16 + r];
#pragma unroll
    for (int r4 = 0; r4 < 4; ++r4) {
      long rowg = row0 + 4 * g + r4;
      long bb = rowg >> shift;
      long n = rowg & mask;
      out[(bb * (NS + NG) + off + n) * DD + ct * 16 + r] =
          fmaxf(acc[ct][r4] + bv, 0.f);
    }
  }
}

// ---------------------------------------------------------------------------
extern "C" void kernel_launch(void* const* d_in, const int* in_sizes, int n_in,
                              void* d_out, int out_size, void* d_ws,
                              size_t ws_size, hipStream_t stream) {
  const float* xs = (const float*)d_in[0];
  const float* xg = (const float*)d_in[1];
  const float* vs = (const float*)d_in[2];
  const float* vg = (const float*)d_in[3];
  const float* Ws_pre = (const float*)d_in[4];
  const float* bs_pre = (const float*)d_in[5];
  const float* Wg_pre = (const float*)d_in[6];
  const float* bg_pre = (const float*)d_in[7];
  const float* Ws_post = (const float*)d_in[8];
  const float* bs_post = (const float*)d_in[9];
  const float* Wg_post = (const float*)d_in[10];
  const float* bg_post = (const float*)d_in[11];
  float* out = (float*)d_out;

  char* p = (char*)d_ws;
  unsigned short* pos1_s = (unsigned short*)p; p += (size_t)BB * NS * 16 * 2;
  unsigned short* pos2_s = (unsigned short*)p; p += (size_t)BB * NS * 16 * 2;
  unsigned short* pos1_g = (unsigned short*)p; p += (size_t)BB * NG * 16 * 2;
  unsigned short* pos2_g = (unsigned short*)p; p += (size_t)BB * NG * 16 * 2;
  unsigned short* WtS_pre = (unsigned short*)p; p += (size_t)128 * 128 * 2;
  unsigned short* WtG_pre = (unsigned short*)p; p += (size_t)128 * 128 * 2;
  unsigned short* WtS_post = (unsigned short*)p; p += (size_t)128 * 256 * 2;
  unsigned short* WtG_post = (unsigned short*)p; p += (size_t)128 * 256 * 2;
  unsigned short* xg_h = (unsigned short*)p; p += (size_t)BB * NG * DD * 2;
  unsigned short* xg_hT = (unsigned short*)p; p += (size_t)BB * NG * DD * 2;
  unsigned short* xs_hT = (unsigned short*)p; p += (size_t)BB * NS * DD * 2;
  unsigned short* xg_o = (unsigned short*)p; p += (size_t)BB * NG * DD * 2;
  float* rsinv = (float*)p; p += (size_t)BB * NS * 4;
  // region R: [xs_h | xs_o] — dead after post_s — reused as msg_g partials
  unsigned short* xs_h = (unsigned short*)p;
  unsigned short* xs_o = xs_h + (size_t)BB * NS * DD;
  unsigned short* part = xs_h;  // SPLITG * BB*NG*DD = 2 * BB*NS*DD exactly
  p += (size_t)2 * BB * NS * DD * 2;

  prep_k<<<(BB * (NS + NG)) / 256 + 98304 / 256, 256, 0, stream>>>(
      vs, vg, Ws_pre, Wg_pre, Ws_post, Wg_post, pos1_s, pos2_s, pos1_g,
      pos2_g, WtS_pre, WtG_pre, WtS_post, WtG_post);
  pre_mfma_k<<<(BB * NS + BB * NG) / 64, 256, 0, stream>>>(
      xs, xg, WtS_pre, WtG_pre, bs_pre, bg_pre, xs_h, xg_h);
  transpose_k<<<BB * NG / 64, 256, 0, stream>>>(xg_h, xg_hT, BB * NG, nullptr);
  msg_s_k<<<dim3(NS / 128, BB), 256, 0, stream>>>(pos1_g, pos2_s, xg_hT, xs_o,
                                                  rsinv);
  transpose_k<<<BB * NS / 64, 256, 0, stream>>>(xs_h, xs_hT, BB * NS, rsinv);
  post_mfma_k<<<BB * NS / 64, 256, 0, stream>>>(xs_h, xs_o, WtS_post, bs_post,
                                                out, 14, NS - 1, 0);
  msg_g_k<<<dim3(NG / 128, BB, SPLITG), 256, 0, stream>>>(pos1_s, pos2_g,
                                                          xs_hT, part);
  reduce_k<<<(BB * NG * DD) / 8 / 256, 256, 0, stream>>>(part, xg_o);
  post_mfma_k<<<BB * NG / 64, 256, 0, stream>>>(xg_h, xg_o, WtG_post, bg_post,
                                                out, 11, NG - 1, NS);
}